// Round 2
// baseline (281.426 us; speedup 1.0000x reference)
//
#include <hip/hip_runtime.h>
#include <hip/hip_bf16.h>

typedef __bf16 bf16x8 __attribute__((ext_vector_type(8)));
typedef float f32x4 __attribute__((ext_vector_type(4)));
typedef unsigned short ushort8 __attribute__((ext_vector_type(8)));

#define B_    4
#define Q_    100
#define QPAD  112
#define D_    128
#define C_    20
#define N_    262144
#define TN    128
#define LROW  136   // padded LDS row (ushorts): 272B stride -> 2-way bank aliasing (free)
#define LN_EPS 1e-5f

// ---------------- Kernel 1: LayerNorm + MLP head + class head ----------------
// One block per (b, q) row. Writes outputs_class to d_out and split-bf16
// mask_embed (hi/lo, padded to QPAD with zeros) to workspace.
__global__ __launch_bounds__(128) void head_kernel(
    const float* __restrict__ qf,
    const float* __restrict__ gamma, const float* __restrict__ beta,
    const float* __restrict__ W1, const float* __restrict__ b1,
    const float* __restrict__ W2, const float* __restrict__ b2,
    const float* __restrict__ Wc, const float* __restrict__ bc,
    float* __restrict__ out_class,
    unsigned short* __restrict__ me_hi, unsigned short* __restrict__ me_lo)
{
    const int q = blockIdx.x;   // 0..QPAD-1
    const int b = blockIdx.y;   // 0..3
    const int t = threadIdx.x;  // 0..127

    unsigned short* mh = me_hi + (b * QPAD + q) * D_;
    unsigned short* ml = me_lo + (b * QPAD + q) * D_;
    if (q >= Q_) { mh[t] = 0; ml[t] = 0; return; }  // zero pad rows (uniform branch)

    __shared__ float red[D_];
    __shared__ float qs[D_];
    __shared__ float hs[D_];

    const float x = qf[(b * Q_ + q) * D_ + t];

    // mean
    red[t] = x;
    __syncthreads();
    #pragma unroll
    for (int s = 64; s > 0; s >>= 1) { if (t < s) red[t] += red[t + s]; __syncthreads(); }
    const float mu = red[0] * (1.0f / 128.0f);
    __syncthreads();
    // variance (population, matches jnp.var)
    const float xc = x - mu;
    red[t] = xc * xc;
    __syncthreads();
    #pragma unroll
    for (int s = 64; s > 0; s >>= 1) { if (t < s) red[t] += red[t + s]; __syncthreads(); }
    const float var = red[0] * (1.0f / 128.0f);

    const float xn = xc * rsqrtf(var + LN_EPS) * gamma[t] + beta[t];
    qs[t] = xn;
    __syncthreads();

    // h = relu(qn @ W1^T + b1)   (thread t computes output feature t)
    {
        const float4* wr = (const float4*)(W1 + t * D_);
        float p0 = 0.f, p1 = 0.f, p2 = 0.f, p3 = 0.f;
        #pragma unroll
        for (int d4 = 0; d4 < 32; ++d4) {
            const float4 w = wr[d4];
            const int d = d4 * 4;
            p0 = fmaf(w.x, qs[d + 0], p0);
            p1 = fmaf(w.y, qs[d + 1], p1);
            p2 = fmaf(w.z, qs[d + 2], p2);
            p3 = fmaf(w.w, qs[d + 3], p3);
        }
        hs[t] = fmaxf((p0 + p1) + (p2 + p3) + b1[t], 0.0f);
    }
    __syncthreads();

    // mask_embed = h @ W2^T + b2 -> split to bf16 hi/lo (Markidis split)
    {
        const float4* wr = (const float4*)(W2 + t * D_);
        float p0 = 0.f, p1 = 0.f, p2 = 0.f, p3 = 0.f;
        #pragma unroll
        for (int d4 = 0; d4 < 32; ++d4) {
            const float4 w = wr[d4];
            const int d = d4 * 4;
            p0 = fmaf(w.x, hs[d + 0], p0);
            p1 = fmaf(w.y, hs[d + 1], p1);
            p2 = fmaf(w.z, hs[d + 2], p2);
            p3 = fmaf(w.w, hs[d + 3], p3);
        }
        const float me = (p0 + p1) + (p2 + p3) + b2[t];
        const __bf16 hi = (__bf16)me;
        const __bf16 lo = (__bf16)(me - (float)hi);
        mh[t] = __builtin_bit_cast(unsigned short, hi);
        ml[t] = __builtin_bit_cast(unsigned short, lo);
    }

    // class head: outputs_class[b,q,c] = qn . Wc[c] + bc[c]
    if (t < C_) {
        const float4* wr = (const float4*)(Wc + t * D_);
        float p0 = 0.f, p1 = 0.f, p2 = 0.f, p3 = 0.f;
        #pragma unroll
        for (int d4 = 0; d4 < 32; ++d4) {
            const float4 w = wr[d4];
            const int d = d4 * 4;
            p0 = fmaf(w.x, qs[d + 0], p0);
            p1 = fmaf(w.y, qs[d + 1], p1);
            p2 = fmaf(w.z, qs[d + 2], p2);
            p3 = fmaf(w.w, qs[d + 3], p3);
        }
        out_class[(b * Q_ + q) * C_ + t] = (p0 + p1) + (p2 + p3) + bc[t];
    }
}

// ---------------- Kernel 2: ragged point_feats @ mask_embed^T via MFMA ----------------
// grid = (N/TN, B). Block (c, b) handles points [c*TN, (c+1)*TN) that belong to
// batch b (sorted batch_ids -> cheap early exit; per-row mask at store).
// out_masks[n,q] = hi.hi + hi.lo + lo.hi  (split-bf16, ~1e-4 rel err)
__global__ __launch_bounds__(512) void mask_kernel(
    const float* __restrict__ points, const int* __restrict__ bids,
    const unsigned short* __restrict__ me_hi, const unsigned short* __restrict__ me_lo,
    float* __restrict__ outm)
{
    const int b  = blockIdx.y;
    const int n0 = blockIdx.x * TN;

    // sorted batch ids: block is inactive if its chunk doesn't intersect batch b
    if (bids[n0] > b || bids[n0 + TN - 1] < b) return;

    __shared__ unsigned short BH[QPAD][LROW];
    __shared__ unsigned short BL[QPAD][LROW];
    __shared__ int sbid[TN];

    const int tid = threadIdx.x;
    if (tid < TN) sbid[tid] = bids[n0 + tid];

    // stage mask_embed[b] hi/lo into LDS (padded row stride)
    {
        const ushort8* sh = (const ushort8*)(me_hi + b * QPAD * D_);
        const ushort8* sl = (const ushort8*)(me_lo + b * QPAD * D_);
        for (int c = tid; c < QPAD * D_ / 8; c += 512) {
            const int row = c >> 4;      // 16 chunks of 8 ushorts per 128-row
            const int col = c & 15;
            *(ushort8*)&BH[row][col * 8] = sh[c];
            *(ushort8*)&BL[row][col * 8] = sl[c];
        }
    }
    __syncthreads();

    const int wave = tid >> 6;      // 8 waves, one 16-point strip each
    const int lane = tid & 63;
    const int ar   = lane & 15;     // A row within strip
    const int kg   = lane >> 4;     // k-group 0..3

    // Load A (points) fragments global->reg, split fp32 -> bf16 hi/lo on the fly.
    // A frag layout (16x16x32): lane holds A[lane&15][ (lane>>4)*8 + j ], j=0..7
    const float* prow = points + (size_t)(n0 + wave * 16 + ar) * D_;
    bf16x8 AH[4], AL[4];
    #pragma unroll
    for (int kt = 0; kt < 4; ++kt) {
        const int k0 = kt * 32 + kg * 8;
        const float4 f0 = *(const float4*)(prow + k0);
        const float4 f1 = *(const float4*)(prow + k0 + 4);
        const float fv0[4] = {f0.x, f0.y, f0.z, f0.w};
        const float fv1[4] = {f1.x, f1.y, f1.z, f1.w};
        #pragma unroll
        for (int j = 0; j < 4; ++j) {
            const __bf16 h0 = (__bf16)fv0[j];
            AH[kt][j] = h0;
            AL[kt][j] = (__bf16)(fv0[j] - (float)h0);
            const __bf16 h1 = (__bf16)fv1[j];
            AH[kt][j + 4] = h1;
            AL[kt][j + 4] = (__bf16)(fv1[j] - (float)h1);
        }
    }

    // store-row activity (C/D row = (lane>>4)*4 + reg)
    bool act[4];
    long nout[4];
    #pragma unroll
    for (int rr = 0; rr < 4; ++rr) {
        const int pl = wave * 16 + kg * 4 + rr;
        act[rr]  = (sbid[pl] == b);
        nout[rr] = (long)(n0 + pl) * Q_;
    }

    const int qlane = lane & 15;    // C/D col = q within tile
    #pragma unroll
    for (int qt = 0; qt < 7; ++qt) {
        f32x4 acc = {0.f, 0.f, 0.f, 0.f};
        const int qrow = qt * 16 + qlane;
        #pragma unroll
        for (int kt = 0; kt < 4; ++kt) {
            const int kb = kt * 32 + kg * 8;   // B frag: lane holds B[(lane>>4)*8+j][lane&15]
            const bf16x8 bh = __builtin_bit_cast(bf16x8, *(const ushort8*)&BH[qrow][kb]);
            const bf16x8 bl = __builtin_bit_cast(bf16x8, *(const ushort8*)&BL[qrow][kb]);
            acc = __builtin_amdgcn_mfma_f32_16x16x32_bf16(AL[kt], bh, acc, 0, 0, 0);
            acc = __builtin_amdgcn_mfma_f32_16x16x32_bf16(AH[kt], bl, acc, 0, 0, 0);
            acc = __builtin_amdgcn_mfma_f32_16x16x32_bf16(AH[kt], bh, acc, 0, 0, 0);
        }
        if (qrow < Q_) {
            #pragma unroll
            for (int rr = 0; rr < 4; ++rr) {
                if (act[rr]) outm[nout[rr] + qrow] = acc[rr];
            }
        }
    }
}

extern "C" void kernel_launch(void* const* d_in, const int* in_sizes, int n_in,
                              void* d_out, int out_size, void* d_ws, size_t ws_size,
                              hipStream_t stream) {
    const float* qf    = (const float*)d_in[0];
    const float* pf    = (const float*)d_in[1];
    const int*   bids  = (const int*)  d_in[2];
    const float* gamma = (const float*)d_in[3];
    const float* beta  = (const float*)d_in[4];
    const float* W1    = (const float*)d_in[5];
    const float* b1    = (const float*)d_in[6];
    const float* W2    = (const float*)d_in[7];
    const float* b2    = (const float*)d_in[8];
    const float* Wc    = (const float*)d_in[9];
    const float* bc    = (const float*)d_in[10];

    float* out_class = (float*)d_out;                    // [4,100,20]
    float* out_masks = out_class + B_ * Q_ * C_;         // [N,100]

    unsigned short* me_hi = (unsigned short*)d_ws;       // [4,112,128] bf16 bits
    unsigned short* me_lo = me_hi + B_ * QPAD * D_;

    head_kernel<<<dim3(QPAD, B_), 128, 0, stream>>>(
        qf, gamma, beta, W1, b1, W2, b2, Wc, bc, out_class, me_hi, me_lo);

    mask_kernel<<<dim3(N_ / TN, B_), 512, 0, stream>>>(
        pf, bids, me_hi, me_lo, out_masks);
}